// Round 3
// baseline (469.697 us; speedup 1.0000x reference)
//
#include <hip/hip_runtime.h>
#include <math.h>

#define C 256
#define NN 4096
#define T_INV 10.0f
#define NEG_IOU_TH 0.5f
#define SGROUP 32
#define FLATS 2
#define QTILES (NN / (256 * FLATS))   // 8

__device__ __forceinline__ float wave_reduce_sum(float v) {
    #pragma unroll
    for (int off = 32; off > 0; off >>= 1) v += __shfl_xor(v, off, 64);
    return v;
}

// --- prep: normalize sents -> sfT (c-major, s stride-1); block 0 builds
//     scatter maps and zeroes denomq + completion counter. ---------------
__global__ void k_prep(const float* __restrict__ sents,
                       const int* __restrict__ num_sentences,
                       const int* __restrict__ num_targets,
                       int B, int S, int M,
                       float* __restrict__ sfT, int* __restrict__ b2s,
                       int* __restrict__ s2b, int* __restrict__ m2s,
                       float* __restrict__ denomq, int* __restrict__ counter) {
    __shared__ float red[4];
    int s = blockIdx.x, tid = threadIdx.x;
    float v = sents[(size_t)s * C + tid];
    float ssq = wave_reduce_sum(v * v);
    int lane = tid & 63, wave = tid >> 6;
    if (lane == 0) red[wave] = ssq;
    __syncthreads();
    float tot = red[0] + red[1] + red[2] + red[3];
    sfT[(size_t)tid * S + s] = v * (1.0f / fmaxf(sqrtf(tot), 1e-12f));

    if (blockIdx.x == 0) {
        if (tid < S) denomq[tid] = 0.f;
        if (tid == 0) {
            *counter = 0;
            int acc = 0;
            for (int b = 0; b < B; ++b) {
                b2s[b] = acc;
                int nsb = num_sentences[b];
                for (int k = 0; k < nsb; ++k) s2b[acc + k] = b;
                acc += nsb;
            }
            int mi = 0;
            for (int si = 0; si < S; ++si) {
                int nt = num_targets[si];
                for (int k = 0; k < nt; ++k) m2s[mi++] = si;
            }
        }
    }
}

// --- main: blocks [0,nq) = inter-query GEMM+exp; blocks [nq,nq+M) = topk /
//     inter-video. Last-finishing block computes the final loss. ----------
__global__ void __launch_bounds__(256)
k_main(const float* __restrict__ vf, const float* __restrict__ iou2d,
       const float* __restrict__ iou2ds, const int* __restrict__ num_sentences,
       const float* __restrict__ sfT, const int* __restrict__ b2s,
       const int* __restrict__ m2s,
       float* __restrict__ pos, float* __restrict__ negiv,
       float* __restrict__ denomq, int* __restrict__ counter,
       float* __restrict__ out, int S, int B, int M, int nq, int ntot) {
    __shared__ float smem[C * SGROUP];   // q: sT tile (32 KB); topk: tv|sc4
    __shared__ float red[4];
    __shared__ int   sidx[4];
    __shared__ float dw[4][SGROUP];
    __shared__ int   bestflat;
    __shared__ int   amlast;

    int bid = blockIdx.x, tid = threadIdx.x;
    int lane = tid & 63, wave = tid >> 6;

    if (bid < nq) {
        // ================= inter-query part =================
        int tile = bid % QTILES;
        int rem  = bid / QTILES;
        int b    = rem % B;
        int g    = rem / B;
        int sb = b2s[b];
        int ns = num_sentences[b];
        int s0 = g * SGROUP;

        for (int k = tid; k < C * SGROUP; k += 256) {
            int c = k / SGROUP, s = k % SGROUP;
            smem[k] = sfT[(size_t)c * S + s0 + s];
        }
        __syncthreads();

        int flat0 = tile * (256 * FLATS) + tid * FLATS;
        const float2* vp = (const float2*)(vf + (size_t)sb * C * NN + flat0);

        float2 acc[SGROUP];
        #pragma unroll
        for (int s = 0; s < SGROUP; ++s) acc[s] = make_float2(0.f, 0.f);
        float2 ssq = make_float2(0.f, 0.f);

        #pragma unroll 2
        for (int c = 0; c < C; ++c) {
            float2 v = vp[(size_t)c * (NN / 2)];
            ssq.x += v.x * v.x;
            ssq.y += v.y * v.y;
            const float4* sr = (const float4*)&smem[c * SGROUP];
            #pragma unroll
            for (int q = 0; q < SGROUP / 4; ++q) {
                float4 s4 = sr[q];
                acc[q*4+0].x += s4.x * v.x;  acc[q*4+0].y += s4.x * v.y;
                acc[q*4+1].x += s4.y * v.x;  acc[q*4+1].y += s4.y * v.y;
                acc[q*4+2].x += s4.z * v.x;  acc[q*4+2].y += s4.z * v.y;
                acc[q*4+3].x += s4.w * v.x;  acc[q*4+3].y += s4.w * v.y;
            }
        }

        int fA = flat0, fB = flat0 + 1;
        bool vA = ((fA & 63) >= (fA >> 6));
        bool vB = ((fB & 63) >= (fB >> 6));
        float invA = 1.0f / fmaxf(sqrtf(ssq.x), 1e-12f);
        float invB = 1.0f / fmaxf(sqrtf(ssq.y), 1e-12f);

        unsigned long long bitsA = 0ull, bitsB = 0ull;
        for (int i = 0; i < ns; ++i) {
            const float* row = iou2d + (size_t)(sb + i) * NN;
            if (vA && row[fA] > NEG_IOU_TH) bitsA |= (1ull << i);
            if (vB && row[fB] > NEG_IOU_TH) bitsB |= (1ull << i);
        }

        #pragma unroll
        for (int s = 0; s < SGROUP; ++s) {
            int s_abs = s0 + s;
            int rel = s_abs - sb;
            bool inblk = (rel >= 0 && rel < ns);
            float e = 0.f;
            if (vA && !(inblk && ((bitsA >> rel) & 1ull)))
                e += expf(acc[s].x * invA * T_INV);
            if (vB && !(inblk && ((bitsB >> rel) & 1ull)))
                e += expf(acc[s].y * invB * T_INV);
            e = wave_reduce_sum(e);
            if (lane == 0) dw[wave][s] = e;
        }
        __syncthreads();
        if (tid < SGROUP)
            atomicAdd(&denomq[s0 + tid],
                      dw[0][tid] + dw[1][tid] + dw[2][tid] + dw[3][tid]);
    } else {
        // ================= topk / inter-video part =================
        int m = bid - nq;
        int s_m = m2s[m];
        float* tv  = smem;        // [C]
        float* sc4 = smem + C;    // [4][64]

        float bv = -1e30f; int bi = NN;
        #pragma unroll
        for (int j = 0; j < NN / 256; ++j) {
            int flat = tid + j * 256;
            int r = flat >> 6, cc = flat & 63;
            if (cc >= r) {
                float val = iou2ds[(size_t)m * NN + flat];
                if (val > bv || (val == bv && flat < bi)) { bv = val; bi = flat; }
            }
        }
        #pragma unroll
        for (int off = 32; off > 0; off >>= 1) {
            float ov = __shfl_xor(bv, off, 64);
            int   oi = __shfl_xor(bi, off, 64);
            if (ov > bv || (ov == bv && oi < bi)) { bv = ov; bi = oi; }
        }
        if (lane == 0) { red[wave] = bv; sidx[wave] = bi; }
        __syncthreads();
        if (tid == 0) {
            float v0 = red[0]; int i0 = sidx[0];
            for (int w = 1; w < 4; ++w)
                if (red[w] > v0 || (red[w] == v0 && sidx[w] < i0)) { v0 = red[w]; i0 = sidx[w]; }
            bestflat = i0;
        }
        __syncthreads();
        int flat = bestflat;

        float v = vf[((size_t)s_m * C + tid) * NN + flat];
        float ssq = wave_reduce_sum(v * v);
        if (lane == 0) red[wave] = ssq;
        __syncthreads();
        float tot = red[0] + red[1] + red[2] + red[3];
        tv[tid] = v * (1.0f / fmaxf(sqrtf(tot), 1e-12f));
        __syncthreads();

        {
            int s = tid & 63, cg = tid >> 6;
            float d = 0.f;
            for (int j = 0; j < 64; ++j) {
                int c2 = cg * 64 + j;
                d += tv[c2] * sfT[(size_t)c2 * S + s];
            }
            sc4[cg * 64 + s] = d;
        }
        __syncthreads();
        if (tid < 64) {
            float d = sc4[tid] + sc4[64 + tid] + sc4[128 + tid] + sc4[192 + tid];
            if (tid == s_m) atomicExch(&pos[m], d);   // device-scope publish
            float e = (tid == s_m) ? 0.f : expf(d * T_INV);
            e = wave_reduce_sum(e);
            if (tid == 0) atomicExch(&negiv[m], e);   // device-scope publish
        }
    }

    // ---- completion tail: last block to finish computes the final loss ----
    __syncthreads();   // drains this block's outstanding memory ops
    if (tid == 0) {
        __threadfence();
        int old = atomicAdd(counter, 1);
        amlast = (old == ntot - 1) ? 1 : 0;
    }
    __syncthreads();
    if (!amlast) return;

    __threadfence();
    float val = 0.f;
    for (int m = tid; m < M; m += 256) {
        int s = m2s[m];
        float pl  = atomicAdd(&pos[m], 0.f) * T_INV;       // coherent reads
        float niv = atomicAdd(&negiv[m], 0.f);
        float dq  = atomicAdd(&denomq[s], 0.f);
        float pe = expf(pl);
        val += -(pl - logf(pe + niv)) + -(pl - logf(pe + dq));
    }
    val = wave_reduce_sum(val);
    if (lane == 0) dw[0][wave] = val;
    __syncthreads();
    if (tid == 0) out[0] = (dw[0][0] + dw[0][1] + dw[0][2] + dw[0][3]) / (float)M;
}

extern "C" void kernel_launch(void* const* d_in, const int* in_sizes, int n_in,
                              void* d_out, int out_size, void* d_ws, size_t ws_size,
                              hipStream_t stream) {
    const float* video_feats   = (const float*)d_in[0];
    const float* sents_feats   = (const float*)d_in[1];
    const float* iou2d         = (const float*)d_in[2];
    const float* iou2ds        = (const float*)d_in[3];
    const int*   num_sentences = (const int*)d_in[4];
    const int*   num_targets   = (const int*)d_in[5];
    // d_in[6] = mask2d: statically triu(ones(64,64)); computed as cc>=r in-kernel.

    const int S = in_sizes[2] / NN;   // 64
    const int B = in_sizes[4];        // 16
    const int M = in_sizes[3] / NN;   // 128

    float* sfT    = (float*)d_ws;              // C*S
    float* pos    = sfT + (size_t)C * 64;
    float* negiv  = pos + M;
    float* denomq = negiv + M;
    int*   b2s    = (int*)(denomq + S);
    int*   s2b    = b2s + B;
    int*   m2s    = s2b + S;
    int*   counter = m2s + M;

    const int nq   = QTILES * B * (S / SGROUP);   // 8*16*2 = 256
    const int ntot = nq + M;                      // 384

    k_prep<<<S, C, 0, stream>>>(sents_feats, num_sentences, num_targets,
                                B, S, M, sfT, b2s, s2b, m2s, denomq, counter);
    k_main<<<ntot, 256, 0, stream>>>(video_feats, iou2d, iou2ds, num_sentences,
                                     sfT, b2s, m2s, pos, negiv, denomq, counter,
                                     (float*)d_out, S, B, M, nq, ntot);
}

// Round 4
// 413.987 us; speedup vs baseline: 1.1346x; 1.1346x over previous
//
#include <hip/hip_runtime.h>
#include <math.h>

#define C 256
#define NN 4096
#define T_INV 10.0f
#define NEG_IOU_TH 0.5f
#define SGROUP 16
#define FLATS 2
#define QTILES (NN / (256 * FLATS))   // 8

__device__ __forceinline__ float wave_reduce_sum(float v) {
    #pragma unroll
    for (int off = 32; off > 0; off >>= 1) v += __shfl_xor(v, off, 64);
    return v;
}

// --- prep: normalize sents -> sfT (c-major, s stride-1); block 0 builds
//     scatter maps and zeroes denomq + completion counter. ---------------
__global__ void k_prep(const float* __restrict__ sents,
                       const int* __restrict__ num_sentences,
                       const int* __restrict__ num_targets,
                       int B, int S, int M,
                       float* __restrict__ sfT, int* __restrict__ b2s,
                       int* __restrict__ s2b, int* __restrict__ m2s,
                       float* __restrict__ denomq, int* __restrict__ counter) {
    __shared__ float red[4];
    int s = blockIdx.x, tid = threadIdx.x;
    float v = sents[(size_t)s * C + tid];
    float ssq = wave_reduce_sum(v * v);
    int lane = tid & 63, wave = tid >> 6;
    if (lane == 0) red[wave] = ssq;
    __syncthreads();
    float tot = red[0] + red[1] + red[2] + red[3];
    sfT[(size_t)tid * S + s] = v * (1.0f / fmaxf(sqrtf(tot), 1e-12f));

    if (blockIdx.x == 0) {
        if (tid < S) denomq[tid] = 0.f;
        if (tid == 0) {
            *counter = 0;
            int acc = 0;
            for (int b = 0; b < B; ++b) {
                b2s[b] = acc;
                int nsb = num_sentences[b];
                for (int k = 0; k < nsb; ++k) s2b[acc + k] = b;
                acc += nsb;
            }
            int mi = 0;
            for (int si = 0; si < S; ++si) {
                int nt = num_targets[si];
                for (int k = 0; k < nt; ++k) m2s[mi++] = si;
            }
        }
    }
}

// --- main: blocks [0,M) = topk/inter-video (latency-heavy, start first);
//     blocks [M, M+nq) = inter-query GEMM+exp.
//     Last-finishing block computes the final loss. ----------------------
__global__ void __launch_bounds__(256)
k_main(const float* __restrict__ vf, const float* __restrict__ iou2d,
       const float* __restrict__ iou2ds, const int* __restrict__ num_sentences,
       const float* __restrict__ sfT, const int* __restrict__ b2s,
       const int* __restrict__ m2s,
       float* __restrict__ pos, float* __restrict__ negiv,
       float* __restrict__ denomq, int* __restrict__ counter,
       float* __restrict__ out, int S, int B, int M, int nq, int ntot) {
    __shared__ float smem[C * SGROUP];   // q: sT tile (16 KB); topk: tv|sc4
    __shared__ float red[4];
    __shared__ int   sidx[4];
    __shared__ float dw[4][SGROUP];
    __shared__ int   bestflat;
    __shared__ int   amlast;

    int bid = blockIdx.x, tid = threadIdx.x;
    int lane = tid & 63, wave = tid >> 6;

    if (bid >= M) {
        // ================= inter-query part =================
        int qb   = bid - M;
        int tile = qb % QTILES;
        int rem  = qb / QTILES;
        int b    = rem % B;
        int g    = rem / B;
        int sb = b2s[b];
        int ns = num_sentences[b];
        int s0 = g * SGROUP;

        for (int k = tid; k < C * SGROUP; k += 256) {
            int c = k / SGROUP, s = k % SGROUP;
            smem[k] = sfT[(size_t)c * S + s0 + s];
        }
        __syncthreads();

        int flat0 = tile * (256 * FLATS) + tid * FLATS;
        const float2* vp = (const float2*)(vf + (size_t)sb * C * NN + flat0);

        float2 acc[SGROUP];
        #pragma unroll
        for (int s = 0; s < SGROUP; ++s) acc[s] = make_float2(0.f, 0.f);
        float ssx = 0.f, ssy = 0.f;

        #pragma unroll 4
        for (int c = 0; c < C; ++c) {
            float2 v = vp[(size_t)c * (NN / 2)];
            ssx += v.x * v.x;
            ssy += v.y * v.y;
            const float4* sr = (const float4*)&smem[c * SGROUP];
            #pragma unroll
            for (int q = 0; q < SGROUP / 4; ++q) {
                float4 s4 = sr[q];
                acc[q*4+0].x += s4.x * v.x;  acc[q*4+0].y += s4.x * v.y;
                acc[q*4+1].x += s4.y * v.x;  acc[q*4+1].y += s4.y * v.y;
                acc[q*4+2].x += s4.z * v.x;  acc[q*4+2].y += s4.z * v.y;
                acc[q*4+3].x += s4.w * v.x;  acc[q*4+3].y += s4.w * v.y;
            }
        }

        int fA = flat0, fB = flat0 + 1;
        bool vA = ((fA & 63) >= (fA >> 6));
        bool vB = ((fB & 63) >= (fB >> 6));
        float invA = 1.0f / fmaxf(sqrtf(ssx), 1e-12f);
        float invB = 1.0f / fmaxf(sqrtf(ssy), 1e-12f);

        unsigned long long bitsA = 0ull, bitsB = 0ull;
        for (int i = 0; i < ns; ++i) {
            const float* row = iou2d + (size_t)(sb + i) * NN;
            if (vA && row[fA] > NEG_IOU_TH) bitsA |= (1ull << i);
            if (vB && row[fB] > NEG_IOU_TH) bitsB |= (1ull << i);
        }

        #pragma unroll
        for (int s = 0; s < SGROUP; ++s) {
            int s_abs = s0 + s;
            int rel = s_abs - sb;
            bool inblk = (rel >= 0 && rel < ns);
            float e = 0.f;
            if (vA && !(inblk && ((bitsA >> rel) & 1ull)))
                e += expf(acc[s].x * invA * T_INV);
            if (vB && !(inblk && ((bitsB >> rel) & 1ull)))
                e += expf(acc[s].y * invB * T_INV);
            e = wave_reduce_sum(e);
            if (lane == 0) dw[wave][s] = e;
        }
        __syncthreads();
        if (tid < SGROUP)
            atomicAdd(&denomq[s0 + tid],
                      dw[0][tid] + dw[1][tid] + dw[2][tid] + dw[3][tid]);
    } else {
        // ================= topk / inter-video part =================
        int m = bid;
        int s_m = m2s[m];
        float* tv  = smem;        // [C]
        float* sc4 = smem + C;    // [4][64]

        float bv = -1e30f; int bi = NN;
        #pragma unroll
        for (int j = 0; j < NN / 256; ++j) {
            int flat = tid + j * 256;
            int r = flat >> 6, cc = flat & 63;
            if (cc >= r) {
                float val = iou2ds[(size_t)m * NN + flat];
                if (val > bv || (val == bv && flat < bi)) { bv = val; bi = flat; }
            }
        }
        #pragma unroll
        for (int off = 32; off > 0; off >>= 1) {
            float ov = __shfl_xor(bv, off, 64);
            int   oi = __shfl_xor(bi, off, 64);
            if (ov > bv || (ov == bv && oi < bi)) { bv = ov; bi = oi; }
        }
        if (lane == 0) { red[wave] = bv; sidx[wave] = bi; }
        __syncthreads();
        if (tid == 0) {
            float v0 = red[0]; int i0 = sidx[0];
            for (int w = 1; w < 4; ++w)
                if (red[w] > v0 || (red[w] == v0 && sidx[w] < i0)) { v0 = red[w]; i0 = sidx[w]; }
            bestflat = i0;
        }
        __syncthreads();
        int flat = bestflat;

        float v = vf[((size_t)s_m * C + tid) * NN + flat];
        float ssq = wave_reduce_sum(v * v);
        if (lane == 0) red[wave] = ssq;
        __syncthreads();
        float tot = red[0] + red[1] + red[2] + red[3];
        tv[tid] = v * (1.0f / fmaxf(sqrtf(tot), 1e-12f));
        __syncthreads();

        {
            int s = tid & 63, cg = tid >> 6;
            float d = 0.f;
            for (int j = 0; j < 64; ++j) {
                int c2 = cg * 64 + j;
                d += tv[c2] * sfT[(size_t)c2 * S + s];
            }
            sc4[cg * 64 + s] = d;
        }
        __syncthreads();
        if (tid < 64) {
            float d = sc4[tid] + sc4[64 + tid] + sc4[128 + tid] + sc4[192 + tid];
            if (tid == s_m) atomicExch(&pos[m], d);   // device-scope publish
            float e = (tid == s_m) ? 0.f : expf(d * T_INV);
            e = wave_reduce_sum(e);
            if (tid == 0) atomicExch(&negiv[m], e);   // device-scope publish
        }
    }

    // ---- completion tail: last block to finish computes the final loss ----
    __syncthreads();   // drains this block's outstanding memory ops
    if (tid == 0) {
        __threadfence();
        int old = atomicAdd(counter, 1);
        amlast = (old == ntot - 1) ? 1 : 0;
    }
    __syncthreads();
    if (!amlast) return;

    __threadfence();
    float val = 0.f;
    for (int m = tid; m < M; m += 256) {
        int s = m2s[m];
        float pl  = atomicAdd(&pos[m], 0.f) * T_INV;       // coherent reads
        float niv = atomicAdd(&negiv[m], 0.f);
        float dq  = atomicAdd(&denomq[s], 0.f);
        float pe = expf(pl);
        val += -(pl - logf(pe + niv)) + -(pl - logf(pe + dq));
    }
    val = wave_reduce_sum(val);
    if (lane == 0) dw[0][wave] = val;
    __syncthreads();
    if (tid == 0) out[0] = (dw[0][0] + dw[0][1] + dw[0][2] + dw[0][3]) / (float)M;
}

extern "C" void kernel_launch(void* const* d_in, const int* in_sizes, int n_in,
                              void* d_out, int out_size, void* d_ws, size_t ws_size,
                              hipStream_t stream) {
    const float* video_feats   = (const float*)d_in[0];
    const float* sents_feats   = (const float*)d_in[1];
    const float* iou2d         = (const float*)d_in[2];
    const float* iou2ds        = (const float*)d_in[3];
    const int*   num_sentences = (const int*)d_in[4];
    const int*   num_targets   = (const int*)d_in[5];
    // d_in[6] = mask2d: statically triu(ones(64,64)); computed as cc>=r in-kernel.

    const int S = in_sizes[2] / NN;   // 64
    const int B = in_sizes[4];        // 16
    const int M = in_sizes[3] / NN;   // 128

    float* sfT    = (float*)d_ws;              // C*S
    float* pos    = sfT + (size_t)C * 64;
    float* negiv  = pos + M;
    float* denomq = negiv + M;
    int*   b2s    = (int*)(denomq + S);
    int*   s2b    = b2s + B;
    int*   m2s    = s2b + S;
    int*   counter = m2s + M;

    const int nq   = QTILES * B * (S / SGROUP);   // 8*16*4 = 512
    const int ntot = M + nq;                      // 640

    k_prep<<<S, C, 0, stream>>>(sents_feats, num_sentences, num_targets,
                                B, S, M, sfT, b2s, s2b, m2s, denomq, counter);
    k_main<<<ntot, 256, 0, stream>>>(video_feats, iou2d, iou2ds, num_sentences,
                                     sfT, b2s, m2s, pos, negiv, denomq, counter,
                                     (float*)d_out, S, B, M, nq, ntot);
}

// Round 5
// 385.202 us; speedup vs baseline: 1.2194x; 1.0747x over previous
//
#include <hip/hip_runtime.h>
#include <math.h>

#define C 256
#define NN 4096
#define T_INV 10.0f
#define NEG_IOU_TH 0.5f
#define SGROUP 8
#define FLATS 2
#define QTILES (NN / (256 * FLATS))   // 8

__device__ __forceinline__ float wave_reduce_sum(float v) {
    #pragma unroll
    for (int off = 32; off > 0; off >>= 1) v += __shfl_xor(v, off, 64);
    return v;
}

// --- prep: normalize sents -> sfT (c-major, s stride-1); block 0 builds
//     scatter maps and zeroes denomq + completion counter. ---------------
__global__ void k_prep(const float* __restrict__ sents,
                       const int* __restrict__ num_sentences,
                       const int* __restrict__ num_targets,
                       int B, int S, int M,
                       float* __restrict__ sfT, int* __restrict__ b2s,
                       int* __restrict__ s2b, int* __restrict__ m2s,
                       float* __restrict__ denomq, int* __restrict__ counter) {
    __shared__ float red[4];
    int s = blockIdx.x, tid = threadIdx.x;
    float v = sents[(size_t)s * C + tid];
    float ssq = wave_reduce_sum(v * v);
    int lane = tid & 63, wave = tid >> 6;
    if (lane == 0) red[wave] = ssq;
    __syncthreads();
    float tot = red[0] + red[1] + red[2] + red[3];
    sfT[(size_t)tid * S + s] = v * (1.0f / fmaxf(sqrtf(tot), 1e-12f));

    if (blockIdx.x == 0) {
        if (tid < S) denomq[tid] = 0.f;
        if (tid == 0) {
            *counter = 0;
            int acc = 0;
            for (int b = 0; b < B; ++b) {
                b2s[b] = acc;
                int nsb = num_sentences[b];
                for (int k = 0; k < nsb; ++k) s2b[acc + k] = b;
                acc += nsb;
            }
            int mi = 0;
            for (int si = 0; si < S; ++si) {
                int nt = num_targets[si];
                for (int k = 0; k < nt; ++k) m2s[mi++] = si;
            }
        }
    }
}

// --- main: blocks [0,M) = topk/inter-video (latency-heavy, start first);
//     blocks [M, M+nq) = inter-query GEMM+exp.
//     Last-finishing block computes the final loss. ----------------------
__global__ void __launch_bounds__(256)
k_main(const float* __restrict__ vf, const float* __restrict__ iou2d,
       const float* __restrict__ iou2ds, const int* __restrict__ num_sentences,
       const float* __restrict__ sfT, const int* __restrict__ b2s,
       const int* __restrict__ m2s,
       float* __restrict__ pos, float* __restrict__ negiv,
       float* __restrict__ denomq, int* __restrict__ counter,
       float* __restrict__ out, int S, int B, int M, int nq, int ntot) {
    __shared__ float smem[C * SGROUP];   // q: sT tile (8 KB); topk: tv|sc4
    __shared__ float red[4];
    __shared__ int   sidx[4];
    __shared__ float dw[4][SGROUP];
    __shared__ int   bestflat;
    __shared__ int   amlast;

    int bid = blockIdx.x, tid = threadIdx.x;
    int lane = tid & 63, wave = tid >> 6;

    if (bid >= M) {
        // ================= inter-query part =================
        int qb   = bid - M;
        int tile = qb % QTILES;
        int rem  = qb / QTILES;
        int b    = rem % B;
        int g    = rem / B;
        int sb = b2s[b];
        int ns = num_sentences[b];
        int s0 = g * SGROUP;

        for (int k = tid; k < C * SGROUP; k += 256) {
            int c = k / SGROUP, s = k % SGROUP;
            smem[k] = sfT[(size_t)c * S + s0 + s];
        }
        __syncthreads();

        int flat0 = tile * (256 * FLATS) + tid * FLATS;
        const float2* vp = (const float2*)(vf + (size_t)sb * C * NN + flat0);

        float2 acc[SGROUP];
        #pragma unroll
        for (int s = 0; s < SGROUP; ++s) acc[s] = make_float2(0.f, 0.f);
        float ssx = 0.f, ssy = 0.f;

        #pragma unroll 4
        for (int c = 0; c < C; ++c) {
            float2 v = vp[(size_t)c * (NN / 2)];
            ssx += v.x * v.x;
            ssy += v.y * v.y;
            const float4* sr = (const float4*)&smem[c * SGROUP];
            #pragma unroll
            for (int q = 0; q < SGROUP / 4; ++q) {
                float4 s4 = sr[q];
                acc[q*4+0].x += s4.x * v.x;  acc[q*4+0].y += s4.x * v.y;
                acc[q*4+1].x += s4.y * v.x;  acc[q*4+1].y += s4.y * v.y;
                acc[q*4+2].x += s4.z * v.x;  acc[q*4+2].y += s4.z * v.y;
                acc[q*4+3].x += s4.w * v.x;  acc[q*4+3].y += s4.w * v.y;
            }
        }

        int fA = flat0, fB = flat0 + 1;
        bool vA = ((fA & 63) >= (fA >> 6));
        bool vB = ((fB & 63) >= (fB >> 6));
        float invA = 1.0f / fmaxf(sqrtf(ssx), 1e-12f);
        float invB = 1.0f / fmaxf(sqrtf(ssy), 1e-12f);

        unsigned long long bitsA = 0ull, bitsB = 0ull;
        for (int i = 0; i < ns; ++i) {
            const float* row = iou2d + (size_t)(sb + i) * NN;
            if (vA && row[fA] > NEG_IOU_TH) bitsA |= (1ull << i);
            if (vB && row[fB] > NEG_IOU_TH) bitsB |= (1ull << i);
        }

        #pragma unroll
        for (int s = 0; s < SGROUP; ++s) {
            int s_abs = s0 + s;
            int rel = s_abs - sb;
            bool inblk = (rel >= 0 && rel < ns);
            float e = 0.f;
            if (vA && !(inblk && ((bitsA >> rel) & 1ull)))
                e += expf(acc[s].x * invA * T_INV);
            if (vB && !(inblk && ((bitsB >> rel) & 1ull)))
                e += expf(acc[s].y * invB * T_INV);
            e = wave_reduce_sum(e);
            if (lane == 0) dw[wave][s] = e;
        }
        __syncthreads();
        if (tid < SGROUP)
            atomicAdd(&denomq[s0 + tid],
                      dw[0][tid] + dw[1][tid] + dw[2][tid] + dw[3][tid]);
    } else {
        // ================= topk / inter-video part =================
        int m = bid;
        int s_m = m2s[m];
        float* tv  = smem;        // [C]
        float* sc4 = smem + C;    // [4][64]

        float bv = -1e30f; int bi = NN;
        #pragma unroll
        for (int j = 0; j < NN / 256; ++j) {
            int flat = tid + j * 256;
            int r = flat >> 6, cc = flat & 63;
            if (cc >= r) {
                float val = iou2ds[(size_t)m * NN + flat];
                if (val > bv || (val == bv && flat < bi)) { bv = val; bi = flat; }
            }
        }
        #pragma unroll
        for (int off = 32; off > 0; off >>= 1) {
            float ov = __shfl_xor(bv, off, 64);
            int   oi = __shfl_xor(bi, off, 64);
            if (ov > bv || (ov == bv && oi < bi)) { bv = ov; bi = oi; }
        }
        if (lane == 0) { red[wave] = bv; sidx[wave] = bi; }
        __syncthreads();
        if (tid == 0) {
            float v0 = red[0]; int i0 = sidx[0];
            for (int w = 1; w < 4; ++w)
                if (red[w] > v0 || (red[w] == v0 && sidx[w] < i0)) { v0 = red[w]; i0 = sidx[w]; }
            bestflat = i0;
        }
        __syncthreads();
        int flat = bestflat;

        float v = vf[((size_t)s_m * C + tid) * NN + flat];
        float ssq = wave_reduce_sum(v * v);
        if (lane == 0) red[wave] = ssq;
        __syncthreads();
        float tot = red[0] + red[1] + red[2] + red[3];
        tv[tid] = v * (1.0f / fmaxf(sqrtf(tot), 1e-12f));
        __syncthreads();

        {
            int s = tid & 63, cg = tid >> 6;
            float d = 0.f;
            for (int j = 0; j < 64; ++j) {
                int c2 = cg * 64 + j;
                d += tv[c2] * sfT[(size_t)c2 * S + s];
            }
            sc4[cg * 64 + s] = d;
        }
        __syncthreads();
        if (tid < 64) {
            float d = sc4[tid] + sc4[64 + tid] + sc4[128 + tid] + sc4[192 + tid];
            if (tid == s_m) atomicExch(&pos[m], d);   // device-scope publish
            float e = (tid == s_m) ? 0.f : expf(d * T_INV);
            e = wave_reduce_sum(e);
            if (tid == 0) atomicExch(&negiv[m], e);   // device-scope publish
        }
    }

    // ---- completion tail: last block to finish computes the final loss ----
    __syncthreads();   // drains this block's outstanding memory ops
    if (tid == 0) {
        __threadfence();
        int old = atomicAdd(counter, 1);
        amlast = (old == ntot - 1) ? 1 : 0;
    }
    __syncthreads();
    if (!amlast) return;

    __threadfence();
    float val = 0.f;
    for (int m = tid; m < M; m += 256) {
        int s = m2s[m];
        float pl  = atomicAdd(&pos[m], 0.f) * T_INV;       // coherent reads
        float niv = atomicAdd(&negiv[m], 0.f);
        float dq  = atomicAdd(&denomq[s], 0.f);
        float pe = expf(pl);
        val += -(pl - logf(pe + niv)) + -(pl - logf(pe + dq));
    }
    val = wave_reduce_sum(val);
    if (lane == 0) dw[0][wave] = val;
    __syncthreads();
    if (tid == 0) out[0] = (dw[0][0] + dw[0][1] + dw[0][2] + dw[0][3]) / (float)M;
}

extern "C" void kernel_launch(void* const* d_in, const int* in_sizes, int n_in,
                              void* d_out, int out_size, void* d_ws, size_t ws_size,
                              hipStream_t stream) {
    const float* video_feats   = (const float*)d_in[0];
    const float* sents_feats   = (const float*)d_in[1];
    const float* iou2d         = (const float*)d_in[2];
    const float* iou2ds        = (const float*)d_in[3];
    const int*   num_sentences = (const int*)d_in[4];
    const int*   num_targets   = (const int*)d_in[5];
    // d_in[6] = mask2d: statically triu(ones(64,64)); computed as cc>=r in-kernel.

    const int S = in_sizes[2] / NN;   // 64
    const int B = in_sizes[4];        // 16
    const int M = in_sizes[3] / NN;   // 128

    float* sfT    = (float*)d_ws;              // C*S
    float* pos    = sfT + (size_t)C * 64;
    float* negiv  = pos + M;
    float* denomq = negiv + M;
    int*   b2s    = (int*)(denomq + S);
    int*   s2b    = b2s + B;
    int*   m2s    = s2b + S;
    int*   counter = m2s + M;

    const int nq   = QTILES * B * (S / SGROUP);   // 8*16*8 = 1024
    const int ntot = M + nq;                      // 1152

    k_prep<<<S, C, 0, stream>>>(sents_feats, num_sentences, num_targets,
                                B, S, M, sfT, b2s, s2b, m2s, denomq, counter);
    k_main<<<ntot, 256, 0, stream>>>(video_feats, iou2d, iou2ds, num_sentences,
                                     sfT, b2s, m2s, pos, negiv, denomq, counter,
                                     (float*)d_out, S, B, M, nq, ntot);
}